// Round 8
// baseline (359.487 us; speedup 1.0000x reference)
//
#include <hip/hip_runtime.h>

typedef unsigned short u16;
typedef unsigned int   u32;
typedef unsigned long long u64;
typedef signed char    i8;

typedef int   i32x4 __attribute__((ext_vector_type(4)));

#define IN_F   4096
#define OUT_F  11008
#define TOKENS 4096

#define BM 256
#define BN 256
#define BKQ 128              // K per tile in i8 elems = 128B rows
#define MT (TOKENS / BM)     // 16
#define NT (OUT_F / BN)      // 43
#define KTILES (IN_F / BKQ)  // 32 phases

// direct global->LDS async copy, 16B per lane; LDS dest = wave-uniform base + lane*16
#define GLOAD_LDS16(g, l)                                                        \
    __builtin_amdgcn_global_load_lds(                                            \
        (const __attribute__((address_space(1))) u32*)(u64)(g),                  \
        (__attribute__((address_space(3))) u32*)(u64)(l), 16, 0, 0)

#define BAR() __builtin_amdgcn_s_barrier()
#define VM(N) asm volatile("s_waitcnt vmcnt(" #N ")" ::: "memory")

__device__ __forceinline__ int pack4(int a, int b, int c, int d) {
    return (a & 255) | ((b & 255) << 8) | ((c & 255) << 16) | (d << 24);
}

// ------- prep_x: f32 -> i8 per-row symmetric quant + exact f32 rowsum --------
__global__ __launch_bounds__(256) void prep_x_kernel(
    const float* __restrict__ x, i8* __restrict__ xq,
    float* __restrict__ rowsum, float* __restrict__ rowscale) {
    const int row = blockIdx.x;
    const int tid = threadIdx.x;
    const float4* xr = reinterpret_cast<const float4*>(x + (size_t)row * IN_F);
    float4 v[4];
    float s = 0.f, mx = 0.f;
#pragma unroll
    for (int i = 0; i < 4; ++i) {
        v[i] = xr[tid * 4 + i];
        s += v[i].x + v[i].y + v[i].z + v[i].w;
        mx = fmaxf(mx, fmaxf(fmaxf(fabsf(v[i].x), fabsf(v[i].y)),
                             fmaxf(fabsf(v[i].z), fabsf(v[i].w))));
    }
#pragma unroll
    for (int off = 32; off > 0; off >>= 1) {
        s += __shfl_down(s, off, 64);
        mx = fmaxf(mx, __shfl_down(mx, off, 64));
    }
    __shared__ float ss[4], sm[4];
    if ((tid & 63) == 0) { ss[tid >> 6] = s; sm[tid >> 6] = mx; }
    __syncthreads();
    const float tot = ss[0] + ss[1] + ss[2] + ss[3];
    const float m4  = fmaxf(fmaxf(sm[0], sm[1]), fmaxf(sm[2], sm[3]));
    const float mg  = fmaxf(m4, 1e-20f);
    const float inv = 127.0f / mg;
    if (tid == 0) { rowsum[row] = tot; rowscale[row] = mg * (1.0f / 127.0f); }
    int4 o;
    int q[16];
#pragma unroll
    for (int i = 0; i < 4; ++i) {
        q[4 * i + 0] = (int)rintf(v[i].x * inv);
        q[4 * i + 1] = (int)rintf(v[i].y * inv);
        q[4 * i + 2] = (int)rintf(v[i].z * inv);
        q[4 * i + 3] = (int)rintf(v[i].w * inv);
    }
    o.x = pack4(q[0], q[1], q[2], q[3]);
    o.y = pack4(q[4], q[5], q[6], q[7]);
    o.z = pack4(q[8], q[9], q[10], q[11]);
    o.w = pack4(q[12], q[13], q[14], q[15]);
    reinterpret_cast<int4*>(xq + (size_t)row * IN_F)[tid] = o;
}

// ---------------- prep_w: int32 (0..255) -> i8 (wq - 128, exact) ----------------
__global__ __launch_bounds__(256) void prep_w_kernel(
    const int* __restrict__ wq, i8* __restrict__ wb) {
    const size_t total16 = (size_t)OUT_F * IN_F / 16;
    size_t i = (size_t)blockIdx.x * blockDim.x + threadIdx.x;
    const size_t stride = (size_t)gridDim.x * blockDim.x;
    const int4* p = reinterpret_cast<const int4*>(wq);
    int4* o = reinterpret_cast<int4*>(wb);
    for (; i < total16; i += stride) {
        int4 a = p[i * 4], b = p[i * 4 + 1], c = p[i * 4 + 2], d = p[i * 4 + 3];
        int4 v;
        v.x = pack4(a.x - 128, a.y - 128, a.z - 128, a.w - 128);
        v.y = pack4(b.x - 128, b.y - 128, b.z - 128, b.w - 128);
        v.z = pack4(c.x - 128, c.y - 128, c.z - 128, c.w - 128);
        v.w = pack4(d.x - 128, d.y - 128, d.z - 128, d.w - 128);
        o[i] = v;
    }
}

// ------- qgemm: i8 16x16x64, 256x256 tile, BKQ=128, ring-2, 8 waves ----------
// y[t,o] = scale_o*sx_t*S_to + scale_o*(128-zero_o)*rowsum_t + bias_o
//
// 32 fat phases (86 sequential over 2.69 grid rounds). Per phase per wave:
//   8 gload_lds (stage tile T+1 -> slot s^1), 24 ds_read_b128 ALL UP FRONT
//   into doubled operand buffers (af0/af1/bfr0/bfr1 -> no WAR serialization),
//   BAR (wait absorbs LDS latency), 64 MFMA back-to-back, VM(0) (stage loads
//   issued ~3000 cyc earlier -> cheap), BAR.
// This breaks r3-r7's per-wave serial [read-wait->MFMA->read-wait->MFMA] chain
// that pinned per-wave MFMA density at 20% (x2 waves/SIMD = the 40% plateau).
//
// LDS: 2 slots x (A 32KB + B 32KB) = 128KB -> 1 block/CU, 8 waves (2/SIMD).
// Rows are 128B = full bank sweep: read 16B-slot = (kh*4+kq) ^ (row&7); 8
// consecutive lanes cover all 8 slots (r4-verified criterion). Stage fetches
// global slot (lane&7)^((lane>>3)&7) so linear gload_lds dest matches (rule 21).

#define LDA2(S)                                                                   \
    _Pragma("unroll") for (int m = 0; m < 8; ++m) {                               \
        const char* rb_ = (const char*)&AS[S][0] +                                \
                          (wr * 128 + m * 16 + l15) * 128;                        \
        af0[m] = *(const i32x4*)(rb_ + (((kq) ^ l7) << 4));                       \
        af1[m] = *(const i32x4*)(rb_ + (((4 + kq) ^ l7) << 4));                   \
    }

#define LDB2(S)                                                                   \
    _Pragma("unroll") for (int n = 0; n < 4; ++n) {                               \
        const char* rb_ = (const char*)&BS[S][0] +                                \
                          (wc * 64 + n * 16 + l15) * 128;                         \
        bfr0[n] = *(const i32x4*)(rb_ + (((kq) ^ l7) << 4));                      \
        bfr1[n] = *(const i32x4*)(rb_ + (((4 + kq) ^ l7) << 4));                  \
    }

#define MFMA_KH(AF, BF)                                                           \
    __builtin_amdgcn_s_setprio(1);                                                \
    _Pragma("unroll") for (int m = 0; m < 8; ++m)                                 \
    _Pragma("unroll") for (int n = 0; n < 4; ++n)                                 \
        acc[m][n] = __builtin_amdgcn_mfma_i32_16x16x64_i8(                        \
            AF[m], BF[n], acc[m][n], 0, 0, 0);                                    \
    __builtin_amdgcn_s_setprio(0);

// A tile = 32KB = 32 chunks of 1KB (8 rows x 128B); wave w stages chunks 4w..4w+3
#define STAGE_A(S, KT)                                                            \
    _Pragma("unroll") for (int j = 0; j < 4; ++j) {                               \
        const int c_ = w * 4 + j;                                                 \
        const i8* g_ = Abase + (size_t)(c_ * 8 + (lane >> 3)) * IN_F +            \
                       (KT) * BKQ + sa;                                           \
        GLOAD_LDS16(g_, (char*)&AS[S][0] + c_ * 1024);                            \
    }

#define STAGE_B(S, KT)                                                            \
    _Pragma("unroll") for (int j = 0; j < 4; ++j) {                               \
        const int c_ = w * 4 + j;                                                 \
        const i8* g_ = Bbase + (size_t)(c_ * 8 + (lane >> 3)) * IN_F +            \
                       (KT) * BKQ + sa;                                           \
        GLOAD_LDS16(g_, (char*)&BS[S][0] + c_ * 1024);                            \
    }

// steady phase: tile T from slot S, stage tile T+1 into slot S^1
#define PHASE(S, T)                                                               \
    STAGE_A((S) ^ 1, (T) + 1);                                                    \
    STAGE_B((S) ^ 1, (T) + 1);                                                    \
    LDA2(S);                                                                      \
    LDB2(S);                                                                      \
    BAR();                                                                        \
    MFMA_KH(af0, bfr0);                                                           \
    MFMA_KH(af1, bfr1);                                                           \
    VM(0);                                                                        \
    BAR();

__global__ __launch_bounds__(512, 1) void qgemm_kernel(
    const i8* __restrict__ Xq, const i8* __restrict__ Wqb,
    const float* __restrict__ rowsum, const float* __restrict__ rowscale,
    const float* __restrict__ scale, const float* __restrict__ zero,
    const float* __restrict__ bias, float* __restrict__ out) {
    __shared__ i8 AS[2][BM * BKQ];  // 2 x 32KB
    __shared__ i8 BS[2][BN * BKQ];  // 2 x 32KB  (128KB -> 1 block/CU)

    // XCD-region grid map: grid = 688 = 8*86; xcd owns 2mt x 43nt, mt-inner
    const int bid = blockIdx.x;
    const int xcd = bid & 7;
    const int g   = bid >> 3;            // 0..85
    const int mt  = xcd * 2 + (g & 1);
    const int nt  = g >> 1;

    const int tid  = threadIdx.x;
    const int w    = tid >> 6;        // wave 0..7
    const int lane = tid & 63;
    const int wr   = w >> 2;          // wave row half 0..1 (128 rows each)
    const int wc   = w & 3;           // wave col quarter 0..3 (64 cols each)
    const int l15  = lane & 15;
    const int l7   = l15 & 7;
    const int kq   = lane >> 4;       // 0..3 (16-elem K slot within 64)
    // stage source swizzle: LDS slot lane&7 at chunk-row lane>>3 holds global
    // slot (lane&7) ^ ((row)&7) = (lane&7) ^ ((lane>>3)&7)   [bytes = elems]
    const int sa = (((lane & 7) ^ ((lane >> 3) & 7)) << 4);

    const i8* Abase = Xq  + (size_t)mt * BM * IN_F;
    const i8* Bbase = Wqb + (size_t)nt * BN * IN_F;

    i32x4 af0[8], af1[8];
    i32x4 bfr0[4], bfr1[4];
    i32x4 acc[8][4];
    const i32x4 zi = {0, 0, 0, 0};
#pragma unroll
    for (int m = 0; m < 8; ++m)
#pragma unroll
        for (int n = 0; n < 4; ++n) acc[m][n] = zi;

    // ---- prologue: stage tile 0 into slot 0 ----
    STAGE_A(0, 0);
    STAGE_B(0, 0);
    VM(0);
    BAR();

    // ---- 31 staged phases + 1 final: tiles 0..31, slot = T&1 ----
    PHASE(0, 0);
#pragma unroll 1
    for (int i = 0; i < 15; ++i) {
        const int t = 2 * i + 1;
        PHASE(1, t);
        PHASE(0, t + 1);
    }
    // final: tile 31 from slot 1, no stage
    LDA2(1);
    LDB2(1);
    BAR();
    MFMA_KH(af0, bfr0);
    MFMA_KH(af1, bfr1);

    // ---- epilogue: C/D layout col = lane&15, row = (lane>>4)*4 + j ----
    // y = scale*sx*S + scale*(128-zero)*rowsum + bias
    const int rowt = mt * BM + wr * 128;
    const int colt = nt * BN + wc * 64;

    float scn[4], bcn[4], ccn[4];
#pragma unroll
    for (int n = 0; n < 4; ++n) {
        const int col = colt + n * 16 + l15;
        scn[n] = scale[col];
        bcn[n] = scn[n] * (128.0f - zero[col]);
        ccn[n] = bias[col];
    }
#pragma unroll
    for (int m = 0; m < 8; ++m) {
#pragma unroll
        for (int j = 0; j < 4; ++j) {
            const int r = rowt + m * 16 + kq * 4 + j;
            const float rsv = rowsum[r];
            const float sxv = rowscale[r];
#pragma unroll
            for (int n = 0; n < 4; ++n) {
                out[(size_t)r * OUT_F + colt + n * 16 + l15] =
                    scn[n] * (sxv * (float)acc[m][n][j]) + bcn[n] * rsv + ccn[n];
            }
        }
    }
}

extern "C" void kernel_launch(void* const* d_in, const int* in_sizes, int n_in,
                              void* d_out, int out_size, void* d_ws, size_t ws_size,
                              hipStream_t stream) {
    const float* x     = (const float*)d_in[0];
    const int*   wq    = (const int*)d_in[1];
    const float* scale = (const float*)d_in[2];
    const float* zero  = (const float*)d_in[3];
    const float* bias  = (const float*)d_in[4];
    float* out = (float*)d_out;

    // workspace: Wq' i8 (45.1 MB) | Xq i8 (16.8 MB) | rowsum (16 KB) | rowscale (16 KB)
    char* ws = (char*)d_ws;
    i8* Wqb = (i8*)ws;
    i8* Xq  = (i8*)(ws + (size_t)OUT_F * IN_F);
    float* rowsum   = (float*)(ws + (size_t)OUT_F * IN_F + (size_t)TOKENS * IN_F);
    float* rowscale = rowsum + TOKENS;

    prep_w_kernel<<<2048, 256, 0, stream>>>(wq, Wqb);
    prep_x_kernel<<<TOKENS, 256, 0, stream>>>(x, Xq, rowsum, rowscale);
    qgemm_kernel<<<MT * NT, 512, 0, stream>>>(Xq, Wqb, rowsum, rowscale,
                                              scale, zero, bias, out);
}

// Round 9
// 239.921 us; speedup vs baseline: 1.4984x; 1.4984x over previous
//
#include <hip/hip_runtime.h>

typedef unsigned short u16;
typedef unsigned int   u32;
typedef unsigned long long u64;
typedef signed char    i8;

typedef int   i32x4 __attribute__((ext_vector_type(4)));

#define IN_F   4096
#define OUT_F  11008
#define TOKENS 4096

#define BM 256
#define BN 256
#define BKQ 128              // K per tile in i8 elems = 128B rows (byte-identical to r2's BK=64 bf16)
#define MT (TOKENS / BM)     // 16
#define NT (OUT_F / BN)      // 43
#define KTILES (IN_F / BKQ)  // 32

// direct global->LDS async copy, 16B per lane; LDS dest = wave-uniform base + lane*16
#define GLOAD_LDS16(g, l)                                                        \
    __builtin_amdgcn_global_load_lds(                                            \
        (const __attribute__((address_space(1))) u32*)(u64)(g),                  \
        (__attribute__((address_space(3))) u32*)(u64)(l), 16, 0, 0)

#define BAR() __builtin_amdgcn_s_barrier()
#define VM(N) asm volatile("s_waitcnt vmcnt(" #N ")" ::: "memory")

__device__ __forceinline__ int pack4(int a, int b, int c, int d) {
    return (a & 255) | ((b & 255) << 8) | ((c & 255) << 16) | (d << 24);
}

// ------- prep_x: f32 -> i8 per-row symmetric quant + exact f32 rowsum --------
__global__ __launch_bounds__(256) void prep_x_kernel(
    const float* __restrict__ x, i8* __restrict__ xq,
    float* __restrict__ rowsum, float* __restrict__ rowscale) {
    const int row = blockIdx.x;
    const int tid = threadIdx.x;
    const float4* xr = reinterpret_cast<const float4*>(x + (size_t)row * IN_F);
    float4 v[4];
    float s = 0.f, mx = 0.f;
#pragma unroll
    for (int i = 0; i < 4; ++i) {
        v[i] = xr[tid * 4 + i];
        s += v[i].x + v[i].y + v[i].z + v[i].w;
        mx = fmaxf(mx, fmaxf(fmaxf(fabsf(v[i].x), fabsf(v[i].y)),
                             fmaxf(fabsf(v[i].z), fabsf(v[i].w))));
    }
#pragma unroll
    for (int off = 32; off > 0; off >>= 1) {
        s += __shfl_down(s, off, 64);
        mx = fmaxf(mx, __shfl_down(mx, off, 64));
    }
    __shared__ float ss[4], sm[4];
    if ((tid & 63) == 0) { ss[tid >> 6] = s; sm[tid >> 6] = mx; }
    __syncthreads();
    const float tot = ss[0] + ss[1] + ss[2] + ss[3];
    const float m4  = fmaxf(fmaxf(sm[0], sm[1]), fmaxf(sm[2], sm[3]));
    const float mg  = fmaxf(m4, 1e-20f);
    const float inv = 127.0f / mg;
    if (tid == 0) { rowsum[row] = tot; rowscale[row] = mg * (1.0f / 127.0f); }
    int4 o;
    int q[16];
#pragma unroll
    for (int i = 0; i < 4; ++i) {
        q[4 * i + 0] = (int)rintf(v[i].x * inv);
        q[4 * i + 1] = (int)rintf(v[i].y * inv);
        q[4 * i + 2] = (int)rintf(v[i].z * inv);
        q[4 * i + 3] = (int)rintf(v[i].w * inv);
    }
    o.x = pack4(q[0], q[1], q[2], q[3]);
    o.y = pack4(q[4], q[5], q[6], q[7]);
    o.z = pack4(q[8], q[9], q[10], q[11]);
    o.w = pack4(q[12], q[13], q[14], q[15]);
    reinterpret_cast<int4*>(xq + (size_t)row * IN_F)[tid] = o;
}

// ---------------- prep_w: int32 (0..255) -> i8 (wq - 128, exact) ----------------
__global__ __launch_bounds__(256) void prep_w_kernel(
    const int* __restrict__ wq, i8* __restrict__ wb) {
    const size_t total16 = (size_t)OUT_F * IN_F / 16;
    size_t i = (size_t)blockIdx.x * blockDim.x + threadIdx.x;
    const size_t stride = (size_t)gridDim.x * blockDim.x;
    const int4* p = reinterpret_cast<const int4*>(wq);
    int4* o = reinterpret_cast<int4*>(wb);
    for (; i < total16; i += stride) {
        int4 a = p[i * 4], b = p[i * 4 + 1], c = p[i * 4 + 2], d = p[i * 4 + 3];
        int4 v;
        v.x = pack4(a.x - 128, a.y - 128, a.z - 128, a.w - 128);
        v.y = pack4(b.x - 128, b.y - 128, b.z - 128, b.w - 128);
        v.z = pack4(c.x - 128, c.y - 128, c.z - 128, c.w - 128);
        v.w = pack4(d.x - 128, d.y - 128, d.z - 128, d.w - 128);
        o[i] = v;
    }
}

// ------- qgemm: r2's 8-phase fine-interleaved schedule, i8 operands ----------
// y[t,o] = scale_o*sx_t*S_to + scale_o*(128-zero_o)*rowsum_t + bias_o
// S_to = sum_k xq[t,k]*wq'[o,k]  (exact i32 via mfma_i32_16x16x64_i8)
//
// Byte-identical to r2 (bf16 BK=64): 256x256 tile, BKQ=128 i8 (128B rows),
// 8 waves (2Mx4N, 128x64 each), LDS 2x(32K A + 32K B) = 128KB, 1 block/CU.
// Region schedule per 2-tile iteration (t even -> buf0, t+1 -> buf1):
//   P1 reads Ah0,Bh0(t)   stages Ah1(t+1)->buf1   VM(10)
//   P2 reads Bh1(t)       stages Ah0(t+2)->buf0   VM(10)
//   P3 reads Ah1(t)       stages Bh0(t+2)->buf0   --
//   P4 reads --           stages Bh1(t+2)->buf0   VM(10)
//   P5 reads Ah0,Bh0(t+1) stages Ah1(t+2)->buf0   VM(10)
//   P6 reads Bh1(t+1)     stages Ah0(t+3)->buf1   VM(10)
//   P7 reads Ah1(t+1)     stages Bh0(t+3)->buf1   --
//   P8 reads --           stages Bh1(t+3)->buf1   VM(10)
// Each phase: 12-or-fewer ds_reads + 1 half-stage (2 gload) interleaved, BAR,
// 16 MFMA (setprio-wrapped), counted VM, BAR. Never drains vmcnt in-loop
// (r8's coarse-split + VM(0) regressed exactly as m196/m218 predict).
// Swizzle (conflicts=0 measured r2): read slot ^= (l15&7) within 128B rows;
// stage pre-swizzles global source slot (lane&7)^(row&7) (rule 21).

#define LDA_HALF(P, MH)                                                           \
    _Pragma("unroll") for (int m = 0; m < 4; ++m)                                 \
    _Pragma("unroll") for (int s = 0; s < 2; ++s)                                 \
        af[m][s] = *(const i32x4*)((const char*)&AS[P][0] +                       \
            ((wr * 128 + (MH) * 64 + m * 16 + l15) * 128 +                        \
             (((s * 4 + kq) ^ (l15 & 7)) << 4)));

#define LDB_HALF(P, NH)                                                           \
    _Pragma("unroll") for (int n = 0; n < 2; ++n)                                 \
    _Pragma("unroll") for (int s = 0; s < 2; ++s)                                 \
        bfr[(NH) * 2 + n][s] = *(const i32x4*)((const char*)&BS[P][0] +           \
            ((wc * 64 + (NH) * 32 + n * 16 + l15) * 128 +                         \
             (((s * 4 + kq) ^ (l15 & 7)) << 4)));

#define MFMA_Q(MH, NH)                                                            \
    __builtin_amdgcn_s_setprio(1);                                                \
    _Pragma("unroll") for (int m = 0; m < 4; ++m)                                 \
    _Pragma("unroll") for (int n = 0; n < 2; ++n)                                 \
    _Pragma("unroll") for (int s = 0; s < 2; ++s)                                 \
        acc[(MH) * 4 + m][(NH) * 2 + n] = __builtin_amdgcn_mfma_i32_16x16x64_i8(  \
            af[m][s], bfr[(NH) * 2 + n][s], acc[(MH) * 4 + m][(NH) * 2 + n],      \
            0, 0, 0);                                                             \
    __builtin_amdgcn_s_setprio(0);

// A half-region H of k-tile KT into buf P: 16KB = 16 chunks of 1KB, 2/wave.
// chunk = H*8 + (i&7) + (i>=8)*16, i = 2w+j  -> rows {H*64..+63} u {128+H*64..}
#define STAGE_A(P, H, KT) {                                                       \
    _Pragma("unroll") for (int j = 0; j < 2; ++j) {                               \
        const int i_ = 2 * w + j;                                                 \
        const int chunk = (((H) * 8 + (i_ & 7) + ((i_ >> 3) << 4)) << 10);        \
        const int row_ = (chunk + lane * 16) >> 7;                                \
        const int cb_ = (((lane & 7) ^ (row_ & 7)) << 4);                         \
        const i8* g_ = Abase + (size_t)row_ * IN_F + (KT) * BKQ + cb_;            \
        GLOAD_LDS16(g_, (char*)&AS[P][0] + chunk);                                \
    } }

// B half-region H: chunk = H*4 + (i&3) + (i>>2)*8
#define STAGE_B(P, H, KT) {                                                       \
    _Pragma("unroll") for (int j = 0; j < 2; ++j) {                               \
        const int i_ = 2 * w + j;                                                 \
        const int chunk = (((H) * 4 + (i_ & 3) + ((i_ >> 2) << 3)) << 10);        \
        const int row_ = (chunk + lane * 16) >> 7;                                \
        const int cb_ = (((lane & 7) ^ (row_ & 7)) << 4);                         \
        const i8* g_ = Bbase + (size_t)row_ * IN_F + (KT) * BKQ + cb_;            \
        GLOAD_LDS16(g_, (char*)&BS[P][0] + chunk);                                \
    } }

__global__ __launch_bounds__(512, 1) void qgemm_kernel(
    const i8* __restrict__ Xq, const i8* __restrict__ Wqb,
    const float* __restrict__ rowsum, const float* __restrict__ rowscale,
    const float* __restrict__ scale, const float* __restrict__ zero,
    const float* __restrict__ bias, float* __restrict__ out) {
    __shared__ i8 AS[2][BM * BKQ];  // 2 x 32KB
    __shared__ i8 BS[2][BN * BKQ];  // 2 x 32KB

    // XCD map (r8-proven FETCH 221MB): xcd owns 2mt x 43nt, nt shared by pairs
    const int bid = blockIdx.x;
    const int xcd = bid & 7;
    const int g   = bid >> 3;            // 0..85
    const int mt  = xcd * 2 + (g & 1);
    const int nt  = g >> 1;

    const int tid  = threadIdx.x;
    const int w    = tid >> 6;        // wave 0..7
    const int lane = tid & 63;
    const int wr   = w >> 2;          // wave row half 0..1 (128 rows each)
    const int wc   = w & 3;           // wave col 0..3 (64 cols each)
    const int l15  = lane & 15;
    const int kq   = lane >> 4;       // 0..3 (16-elem K slot within 64)

    const i8* Abase = Xq  + (size_t)mt * BM * IN_F;
    const i8* Bbase = Wqb + (size_t)nt * BN * IN_F;

    i32x4 af[4][2];
    i32x4 bfr[4][2];
    i32x4 acc[8][4];
    const i32x4 zi = {0, 0, 0, 0};
#pragma unroll
    for (int m = 0; m < 8; ++m)
#pragma unroll
        for (int n = 0; n < 4; ++n) acc[m][n] = zi;

    // ---- prologue: 7 half-stages in steady-state FIFO order ----
    STAGE_A(0, 0, 0);   // Ah0(0)
    STAGE_B(0, 0, 0);   // Bh0(0)
    STAGE_B(0, 1, 0);   // Bh1(0)
    STAGE_A(0, 1, 0);   // Ah1(0)
    STAGE_A(1, 0, 1);   // Ah0(1)
    STAGE_B(1, 0, 1);   // Bh0(1)
    STAGE_B(1, 1, 1);   // Bh1(1)
    VM(10);             // Ah0(0), Bh0(0) landed
    BAR();

    // ---- steady loop: 15 iterations, tiles 0..29 (stages through 31) ----
    for (int i = 0; i < 15; ++i) {
        const int t = 2 * i;
        // P1
        LDA_HALF(0, 0); LDB_HALF(0, 0);
        STAGE_A(1, 1, t + 1);
        BAR();
        MFMA_Q(0, 0);
        VM(10); BAR();
        // P2
        LDB_HALF(0, 1);
        STAGE_A(0, 0, t + 2);
        BAR();
        MFMA_Q(0, 1);
        VM(10); BAR();
        // P3
        LDA_HALF(0, 1);
        STAGE_B(0, 0, t + 2);
        BAR();
        MFMA_Q(1, 0);
        BAR();
        // P4
        STAGE_B(0, 1, t + 2);
        BAR();
        MFMA_Q(1, 1);
        VM(10); BAR();
        // P5
        LDA_HALF(1, 0); LDB_HALF(1, 0);
        STAGE_A(0, 1, t + 2);
        BAR();
        MFMA_Q(0, 0);
        VM(10); BAR();
        // P6
        LDB_HALF(1, 1);
        STAGE_A(1, 0, t + 3);
        BAR();
        MFMA_Q(0, 1);
        VM(10); BAR();
        // P7
        LDA_HALF(1, 1);
        STAGE_B(1, 0, t + 3);
        BAR();
        MFMA_Q(1, 0);
        BAR();
        // P8
        STAGE_B(1, 1, t + 3);
        BAR();
        MFMA_Q(1, 1);
        VM(10); BAR();
    }

    // ---- peeled final iteration: tiles 30 (buf0), 31 (buf1) ----
    // P1
    LDA_HALF(0, 0); LDB_HALF(0, 0);
    STAGE_A(1, 1, 31);
    BAR();
    MFMA_Q(0, 0);
    VM(10); BAR();
    // P2
    LDB_HALF(0, 1);
    BAR();
    MFMA_Q(0, 1);
    VM(8); BAR();
    // P3
    LDA_HALF(0, 1);
    BAR();
    MFMA_Q(1, 0);
    BAR();
    // P4
    BAR();
    MFMA_Q(1, 1);
    VM(4); BAR();
    // P5
    LDA_HALF(1, 0); LDB_HALF(1, 0);
    BAR();
    MFMA_Q(0, 0);
    VM(2); BAR();
    // P6
    LDB_HALF(1, 1);
    BAR();
    MFMA_Q(0, 1);
    VM(0); BAR();
    // P7
    LDA_HALF(1, 1);
    BAR();
    MFMA_Q(1, 0);
    BAR();
    // P8
    BAR();
    MFMA_Q(1, 1);

    // ---- epilogue: C/D layout col = lane&15, row = (lane>>4)*4 + j ----
    // y = scale*sx*S + scale*(128-zero)*rowsum + bias
    const int rowt = mt * BM + wr * 128;
    const int colt = nt * BN + wc * 64;

    float scn[4], bcn[4], ccn[4];
#pragma unroll
    for (int n = 0; n < 4; ++n) {
        const int col = colt + n * 16 + l15;
        scn[n] = scale[col];
        bcn[n] = scn[n] * (128.0f - zero[col]);
        ccn[n] = bias[col];
    }
#pragma unroll
    for (int m = 0; m < 8; ++m) {
#pragma unroll
        for (int j = 0; j < 4; ++j) {
            const int r = rowt + m * 16 + kq * 4 + j;
            const float rsv = rowsum[r];
            const float sxv = rowscale[r];
#pragma unroll
            for (int n = 0; n < 4; ++n) {
                out[(size_t)r * OUT_F + colt + n * 16 + l15] =
                    scn[n] * (sxv * (float)acc[m][n][j]) + bcn[n] * rsv + ccn[n];
            }
        }
    }
}

extern "C" void kernel_launch(void* const* d_in, const int* in_sizes, int n_in,
                              void* d_out, int out_size, void* d_ws, size_t ws_size,
                              hipStream_t stream) {
    const float* x     = (const float*)d_in[0];
    const int*   wq    = (const int*)d_in[1];
    const float* scale = (const float*)d_in[2];
    const float* zero  = (const float*)d_in[3];
    const float* bias  = (const float*)d_in[4];
    float* out = (float*)d_out;

    // workspace: Wq' i8 (45.1 MB) | Xq i8 (16.8 MB) | rowsum (16 KB) | rowscale (16 KB)
    char* ws = (char*)d_ws;
    i8* Wqb = (i8*)ws;
    i8* Xq  = (i8*)(ws + (size_t)OUT_F * IN_F);
    float* rowsum   = (float*)(ws + (size_t)OUT_F * IN_F + (size_t)TOKENS * IN_F);
    float* rowscale = rowsum + TOKENS;

    prep_w_kernel<<<2048, 256, 0, stream>>>(wq, Wqb);
    prep_x_kernel<<<TOKENS, 256, 0, stream>>>(x, Xq, rowsum, rowscale);
    qgemm_kernel<<<MT * NT, 512, 0, stream>>>(Xq, Wqb, rowsum, rowscale,
                                              scale, zero, bias, out);
}

// Round 10
// 239.363 us; speedup vs baseline: 1.5018x; 1.0023x over previous
//
#include <hip/hip_runtime.h>

typedef unsigned short u16;
typedef unsigned int   u32;
typedef unsigned long long u64;
typedef signed char    i8;

typedef int   i32x4 __attribute__((ext_vector_type(4)));

#define IN_F   4096
#define OUT_F  11008
#define TOKENS 4096

#define BM 256
#define BN 256
#define BKQ 128              // K per tile in i8 elems = 128B rows
#define MT (TOKENS / BM)     // 16
#define NT (OUT_F / BN)      // 43
#define KTILES (IN_F / BKQ)  // 32

// direct global->LDS async copy, 16B per lane; LDS dest = wave-uniform base + lane*16
#define GLOAD_LDS16(g, l)                                                        \
    __builtin_amdgcn_global_load_lds(                                            \
        (const __attribute__((address_space(1))) u32*)(u64)(g),                  \
        (__attribute__((address_space(3))) u32*)(u64)(l), 16, 0, 0)

#define BAR() __builtin_amdgcn_s_barrier()
#define VM(N)    asm volatile("s_waitcnt vmcnt(" #N ")" ::: "memory")
#define LGKM(N)  asm volatile("s_waitcnt lgkmcnt(" #N ")" ::: "memory")

__device__ __forceinline__ int pack4(int a, int b, int c, int d) {
    return (a & 255) | ((b & 255) << 8) | ((c & 255) << 16) | (d << 24);
}

// ------- prep_x: f32 -> i8 per-row symmetric quant + exact f32 rowsum --------
__global__ __launch_bounds__(256) void prep_x_kernel(
    const float* __restrict__ x, i8* __restrict__ xq,
    float* __restrict__ rowsum, float* __restrict__ rowscale) {
    const int row = blockIdx.x;
    const int tid = threadIdx.x;
    const float4* xr = reinterpret_cast<const float4*>(x + (size_t)row * IN_F);
    float4 v[4];
    float s = 0.f, mx = 0.f;
#pragma unroll
    for (int i = 0; i < 4; ++i) {
        v[i] = xr[tid * 4 + i];
        s += v[i].x + v[i].y + v[i].z + v[i].w;
        mx = fmaxf(mx, fmaxf(fmaxf(fabsf(v[i].x), fabsf(v[i].y)),
                             fmaxf(fabsf(v[i].z), fabsf(v[i].w))));
    }
#pragma unroll
    for (int off = 32; off > 0; off >>= 1) {
        s += __shfl_down(s, off, 64);
        mx = fmaxf(mx, __shfl_down(mx, off, 64));
    }
    __shared__ float ss[4], sm[4];
    if ((tid & 63) == 0) { ss[tid >> 6] = s; sm[tid >> 6] = mx; }
    __syncthreads();
    const float tot = ss[0] + ss[1] + ss[2] + ss[3];
    const float m4  = fmaxf(fmaxf(sm[0], sm[1]), fmaxf(sm[2], sm[3]));
    const float mg  = fmaxf(m4, 1e-20f);
    const float inv = 127.0f / mg;
    if (tid == 0) { rowsum[row] = tot; rowscale[row] = mg * (1.0f / 127.0f); }
    int4 o;
    int q[16];
#pragma unroll
    for (int i = 0; i < 4; ++i) {
        q[4 * i + 0] = (int)rintf(v[i].x * inv);
        q[4 * i + 1] = (int)rintf(v[i].y * inv);
        q[4 * i + 2] = (int)rintf(v[i].z * inv);
        q[4 * i + 3] = (int)rintf(v[i].w * inv);
    }
    o.x = pack4(q[0], q[1], q[2], q[3]);
    o.y = pack4(q[4], q[5], q[6], q[7]);
    o.z = pack4(q[8], q[9], q[10], q[11]);
    o.w = pack4(q[12], q[13], q[14], q[15]);
    reinterpret_cast<int4*>(xq + (size_t)row * IN_F)[tid] = o;
}

// ---------------- prep_w: int32 (0..255) -> i8 (wq - 128, exact) ----------------
__global__ __launch_bounds__(256) void prep_w_kernel(
    const int* __restrict__ wq, i8* __restrict__ wb) {
    const size_t total16 = (size_t)OUT_F * IN_F / 16;
    size_t i = (size_t)blockIdx.x * blockDim.x + threadIdx.x;
    const size_t stride = (size_t)gridDim.x * blockDim.x;
    const int4* p = reinterpret_cast<const int4*>(wq);
    int4* o = reinterpret_cast<int4*>(wb);
    for (; i < total16; i += stride) {
        int4 a = p[i * 4], b = p[i * 4 + 1], c = p[i * 4 + 2], d = p[i * 4 + 3];
        int4 v;
        v.x = pack4(a.x - 128, a.y - 128, a.z - 128, a.w - 128);
        v.y = pack4(b.x - 128, b.y - 128, b.z - 128, b.w - 128);
        v.z = pack4(c.x - 128, c.y - 128, c.z - 128, c.w - 128);
        v.w = pack4(d.x - 128, d.y - 128, d.z - 128, d.w - 128);
        o[i] = v;
    }
}

// ------- qgemm: 8-phase i8 schedule, m201 wait discipline (VM(6) @ P4/P8) ----
// y[t,o] = scale_o*sx_t*S_to + scale_o*(128-zero_o)*rowsum_t + bias_o
//
// r9 + wait-discipline change ONLY:
//   - vmcnt waits reduced from 6x VM(10)/iter to 2x VM(6) (ends of P4, P8).
//     FIFO audit: P4's VM(6) retires through stage P1 = {Ah0,Bh0,Bh1,Ah1}(t+1)
//     -> covers P5/P6/P7 reads; P8's VM(6) retires through stage P5 =
//     {Ah0,Bh0,Bh1,Ah1}(t+2) -> covers next-iter P1/P2/P3 reads.
//   - lgkmcnt(8) pre-barrier hint in 12-ds_read phases (P1,P5);
//     explicit lgkmcnt(0) after each pre-MFMA barrier (m201 pattern; ds_reads
//     are compiler-visible so dependency waits remain correct regardless).
// Everything else byte-identical to r9 (region schedule, swizzle conflicts=0,
// XCD map FETCH 201MB, epilogue).

#define LDA_HALF(P, MH)                                                           \
    _Pragma("unroll") for (int m = 0; m < 4; ++m)                                 \
    _Pragma("unroll") for (int s = 0; s < 2; ++s)                                 \
        af[m][s] = *(const i32x4*)((const char*)&AS[P][0] +                       \
            ((wr * 128 + (MH) * 64 + m * 16 + l15) * 128 +                        \
             (((s * 4 + kq) ^ (l15 & 7)) << 4)));

#define LDB_HALF(P, NH)                                                           \
    _Pragma("unroll") for (int n = 0; n < 2; ++n)                                 \
    _Pragma("unroll") for (int s = 0; s < 2; ++s)                                 \
        bfr[(NH) * 2 + n][s] = *(const i32x4*)((const char*)&BS[P][0] +           \
            ((wc * 64 + (NH) * 32 + n * 16 + l15) * 128 +                         \
             (((s * 4 + kq) ^ (l15 & 7)) << 4)));

#define MFMA_Q(MH, NH)                                                            \
    __builtin_amdgcn_s_setprio(1);                                                \
    _Pragma("unroll") for (int m = 0; m < 4; ++m)                                 \
    _Pragma("unroll") for (int n = 0; n < 2; ++n)                                 \
    _Pragma("unroll") for (int s = 0; s < 2; ++s)                                 \
        acc[(MH) * 4 + m][(NH) * 2 + n] = __builtin_amdgcn_mfma_i32_16x16x64_i8(  \
            af[m][s], bfr[(NH) * 2 + n][s], acc[(MH) * 4 + m][(NH) * 2 + n],      \
            0, 0, 0);                                                             \
    __builtin_amdgcn_s_setprio(0);

// A half-region H of k-tile KT into buf P: 16 chunks of 1KB, 2/wave.
#define STAGE_A(P, H, KT) {                                                       \
    _Pragma("unroll") for (int j = 0; j < 2; ++j) {                               \
        const int i_ = 2 * w + j;                                                 \
        const int chunk = (((H) * 8 + (i_ & 7) + ((i_ >> 3) << 4)) << 10);        \
        const int row_ = (chunk + lane * 16) >> 7;                                \
        const int cb_ = (((lane & 7) ^ (row_ & 7)) << 4);                         \
        const i8* g_ = Abase + (size_t)row_ * IN_F + (KT) * BKQ + cb_;            \
        GLOAD_LDS16(g_, (char*)&AS[P][0] + chunk);                                \
    } }

// B half-region H: chunk = H*4 + (i&3) + (i>>2)*8
#define STAGE_B(P, H, KT) {                                                       \
    _Pragma("unroll") for (int j = 0; j < 2; ++j) {                               \
        const int i_ = 2 * w + j;                                                 \
        const int chunk = (((H) * 4 + (i_ & 3) + ((i_ >> 2) << 3)) << 10);        \
        const int row_ = (chunk + lane * 16) >> 7;                                \
        const int cb_ = (((lane & 7) ^ (row_ & 7)) << 4);                         \
        const i8* g_ = Bbase + (size_t)row_ * IN_F + (KT) * BKQ + cb_;            \
        GLOAD_LDS16(g_, (char*)&BS[P][0] + chunk);                                \
    } }

__global__ __launch_bounds__(512, 1) void qgemm_kernel(
    const i8* __restrict__ Xq, const i8* __restrict__ Wqb,
    const float* __restrict__ rowsum, const float* __restrict__ rowscale,
    const float* __restrict__ scale, const float* __restrict__ zero,
    const float* __restrict__ bias, float* __restrict__ out) {
    __shared__ i8 AS[2][BM * BKQ];  // 2 x 32KB
    __shared__ i8 BS[2][BN * BKQ];  // 2 x 32KB

    // XCD map: xcd owns 2mt x 43nt
    const int bid = blockIdx.x;
    const int xcd = bid & 7;
    const int g   = bid >> 3;            // 0..85
    const int mt  = xcd * 2 + (g & 1);
    const int nt  = g >> 1;

    const int tid  = threadIdx.x;
    const int w    = tid >> 6;        // wave 0..7
    const int lane = tid & 63;
    const int wr   = w >> 2;          // wave row half 0..1 (128 rows each)
    const int wc   = w & 3;           // wave col 0..3 (64 cols each)
    const int l15  = lane & 15;
    const int kq   = lane >> 4;       // 0..3 (16-elem K slot within 64)

    const i8* Abase = Xq  + (size_t)mt * BM * IN_F;
    const i8* Bbase = Wqb + (size_t)nt * BN * IN_F;

    i32x4 af[4][2];
    i32x4 bfr[4][2];
    i32x4 acc[8][4];
    const i32x4 zi = {0, 0, 0, 0};
#pragma unroll
    for (int m = 0; m < 8; ++m)
#pragma unroll
        for (int n = 0; n < 4; ++n) acc[m][n] = zi;

    // ---- prologue: 7 half-stages in steady-state FIFO order ----
    STAGE_A(0, 0, 0);   // Ah0(0)
    STAGE_B(0, 0, 0);   // Bh0(0)
    STAGE_B(0, 1, 0);   // Bh1(0)
    STAGE_A(0, 1, 0);   // Ah1(0)
    STAGE_A(1, 0, 1);   // Ah0(1)
    STAGE_B(1, 0, 1);   // Bh0(1)
    STAGE_B(1, 1, 1);   // Bh1(1)
    VM(6);              // retires ALL of tile 0 (covers P1-P3 reads)
    BAR();

    // ---- steady loop: 15 iterations, tiles 0..29 (stages through 31) ----
    for (int i = 0; i < 15; ++i) {
        const int t = 2 * i;
        // P1
        LDA_HALF(0, 0); LDB_HALF(0, 0);
        STAGE_A(1, 1, t + 1);
        LGKM(8);
        BAR();
        LGKM(0);
        MFMA_Q(0, 0);
        BAR();
        // P2
        LDB_HALF(0, 1);
        STAGE_A(0, 0, t + 2);
        BAR();
        LGKM(0);
        MFMA_Q(0, 1);
        BAR();
        // P3
        LDA_HALF(0, 1);
        STAGE_B(0, 0, t + 2);
        BAR();
        LGKM(0);
        MFMA_Q(1, 0);
        BAR();
        // P4
        STAGE_B(0, 1, t + 2);
        BAR();
        MFMA_Q(1, 1);
        VM(6); BAR();   // retires {Ah0,Bh0,Bh1,Ah1}(t+1) -> covers P5-P7
        // P5
        LDA_HALF(1, 0); LDB_HALF(1, 0);
        STAGE_A(0, 1, t + 2);
        LGKM(8);
        BAR();
        LGKM(0);
        MFMA_Q(0, 0);
        BAR();
        // P6
        LDB_HALF(1, 1);
        STAGE_A(1, 0, t + 3);
        BAR();
        LGKM(0);
        MFMA_Q(0, 1);
        BAR();
        // P7
        LDA_HALF(1, 1);
        STAGE_B(1, 0, t + 3);
        BAR();
        LGKM(0);
        MFMA_Q(1, 0);
        BAR();
        // P8
        STAGE_B(1, 1, t + 3);
        BAR();
        MFMA_Q(1, 1);
        VM(6); BAR();   // retires {Ah0,Bh0,Bh1,Ah1}(t+2) -> covers next P1-P3
    }

    // ---- peeled final iteration: tiles 30 (buf0), 31 (buf1) ----
    // (tile-30 regions fully retired by last steady VM(6); tile-31 by peel-P4's VM(0))
    // P1
    LDA_HALF(0, 0); LDB_HALF(0, 0);
    STAGE_A(1, 1, 31);
    BAR();
    LGKM(0);
    MFMA_Q(0, 0);
    BAR();
    // P2
    LDB_HALF(0, 1);
    BAR();
    LGKM(0);
    MFMA_Q(0, 1);
    BAR();
    // P3
    LDA_HALF(0, 1);
    BAR();
    LGKM(0);
    MFMA_Q(1, 0);
    BAR();
    // P4
    BAR();
    MFMA_Q(1, 1);
    VM(0); BAR();   // drain: all tile-31 stages landed
    // P5
    LDA_HALF(1, 0); LDB_HALF(1, 0);
    BAR();
    LGKM(0);
    MFMA_Q(0, 0);
    BAR();
    // P6
    LDB_HALF(1, 1);
    BAR();
    LGKM(0);
    MFMA_Q(0, 1);
    BAR();
    // P7
    LDA_HALF(1, 1);
    BAR();
    LGKM(0);
    MFMA_Q(1, 0);
    BAR();
    // P8
    BAR();
    MFMA_Q(1, 1);

    // ---- epilogue: C/D layout col = lane&15, row = (lane>>4)*4 + j ----
    // y = scale*sx*S + scale*(128-zero)*rowsum + bias
    const int rowt = mt * BM + wr * 128;
    const int colt = nt * BN + wc * 64;

    float scn[4], bcn[4], ccn[4];
#pragma unroll
    for (int n = 0; n < 4; ++n) {
        const int col = colt + n * 16 + l15;
        scn[n] = scale[col];
        bcn[n] = scn[n] * (128.0f - zero[col]);
        ccn[n] = bias[col];
    }
#pragma unroll
    for (int m = 0; m < 8; ++m) {
#pragma unroll
        for (int j = 0; j < 4; ++j) {
            const int r = rowt + m * 16 + kq * 4 + j;
            const float rsv = rowsum[r];
            const float sxv = rowscale[r];
#pragma unroll
            for (int n = 0; n < 4; ++n) {
                out[(size_t)r * OUT_F + colt + n * 16 + l15] =
                    scn[n] * (sxv * (float)acc[m][n][j]) + bcn[n] * rsv + ccn[n];
            }
        }
    }
}

extern "C" void kernel_launch(void* const* d_in, const int* in_sizes, int n_in,
                              void* d_out, int out_size, void* d_ws, size_t ws_size,
                              hipStream_t stream) {
    const float* x     = (const float*)d_in[0];
    const int*   wq    = (const int*)d_in[1];
    const float* scale = (const float*)d_in[2];
    const float* zero  = (const float*)d_in[3];
    const float* bias  = (const float*)d_in[4];
    float* out = (float*)d_out;

    // workspace: Wq' i8 (45.1 MB) | Xq i8 (16.8 MB) | rowsum (16 KB) | rowscale (16 KB)
    char* ws = (char*)d_ws;
    i8* Wqb = (i8*)ws;
    i8* Xq  = (i8*)(ws + (size_t)OUT_F * IN_F);
    float* rowsum   = (float*)(ws + (size_t)OUT_F * IN_F + (size_t)TOKENS * IN_F);
    float* rowscale = rowsum + TOKENS;

    prep_w_kernel<<<2048, 256, 0, stream>>>(wq, Wqb);
    prep_x_kernel<<<TOKENS, 256, 0, stream>>>(x, Xq, rowsum, rowscale);
    qgemm_kernel<<<MT * NT, 512, 0, stream>>>(Xq, Wqb, rowsum, rowscale,
                                              scale, zero, bias, out);
}